// Round 7
// baseline (163.434 us; speedup 1.0000x reference)
//
#include <hip/hip_runtime.h>

// Problem dims (fixed by setup_inputs): T=1024, B=8, d=64, n=64
#define T_DIM 1024
#define B_DIM 8
#define D_DIM 64
#define N_DIM 64

typedef float v4f __attribute__((ext_vector_type(4)));

// Chunking: 64 chunks of 16 timesteps (shared by decay lsum and outer cumsum)
#define C_CHUNKS 64
#define C_LEN 16
#define SLAB (B_DIM * D_DIM * N_DIM)  // 32768 floats per chunk slab

// Workspace layout (floats):
//   psum : [64][B][D][N]  at 0          (2097152 floats, 8 MB)
//   pxs  : [64][B][D][N]  at 2097152    (8 MB, exclusive prefix of psum)
//   lsum : [B][64][N]     at 4194304    (32768 floats)
// total ~17 MB
#define WS_PSUM 0
#define WS_PXS (C_CHUNKS * SLAB)
#define WS_LSUM (2 * C_CHUNKS * SLAB)

// ---------------------------------------------------------------------------
// A: per-(b, t-chunk) sums of log(max(alpha,1e-8)). lane = n, coalesced rows.
// ---------------------------------------------------------------------------
__global__ __launch_bounds__(64) void lsum_kernel(
    const float* __restrict__ alpha, float* __restrict__ lsum) {
  const int b = blockIdx.x >> 6;
  const int c = blockIdx.x & 63;
  const int n = threadIdx.x;

  float s = 0.f;
#pragma unroll
  for (int i = 0; i < C_LEN; ++i) {
    const int t = c * C_LEN + i;
    s += __logf(fmaxf(alpha[((size_t)t * B_DIM + b) * N_DIM + n], 1e-8f));
  }
  lsum[((size_t)b * C_CHUNKS + c) * N_DIM + n] = s;
}

// ---------------------------------------------------------------------------
// Shared staging: recompute this chunk's w-tile [16][64] and v-tile [16][16]
// into LDS. w[t][n] = k[t][n] * exp(prefix_log) / (exp(total_log)+1e-8).
// Threads 0..63 (lane = n) do the 16-step serial decay chain; all 256 threads
// load one v element. Transcendental cost ~32 fast ops per active lane.
// ---------------------------------------------------------------------------
__device__ __forceinline__ void stage_w_v(
    int b, int c, int dt, int tid,
    const float* __restrict__ v, const float* __restrict__ alpha,
    const float* __restrict__ kk, const float* __restrict__ lsum,
    float (*w_t)[N_DIM], float (*v_t)[16]) {
  // v-tile: one element per thread. i = t-step, dl = d_loc.
  {
    const int i = tid >> 4;
    const int dl = tid & 15;
    v_t[i][dl] =
        v[((size_t)(c * C_LEN + i) * B_DIM + b) * D_DIM + dt * 16 + dl];
  }
  if (tid < 64) {
    const int n = tid;
    const float* __restrict__ lp = lsum + (size_t)b * C_CHUNKS * N_DIM + n;
    float pre = 0.f, tot = 0.f;
#pragma unroll
    for (int j = 0; j < C_CHUNKS; ++j) {
      const float sj = lp[(size_t)j * N_DIM];
      tot += sj;
      pre += (j < c) ? sj : 0.f;
    }
    // Reference f32 numerics: exp(tot) underflows to 0 -> denom = 1e-8.
    const float invden = 1.0f / (__expf(tot) + 1e-8f);
    float cum = pre;
#pragma unroll
    for (int i = 0; i < C_LEN; ++i) {
      const size_t idx = ((size_t)(c * C_LEN + i) * B_DIM + b) * N_DIM + n;
      cum += __logf(fmaxf(alpha[idx], 1e-8f));
      w_t[i][n] = kk[idx] * __expf(cum) * invden;
    }
  }
}

// ---------------------------------------------------------------------------
// B: per-chunk partial sums psum[c] = sum_{t in chunk} v*w, from LDS tiles.
// Grid = 64*8*4 = 2048 blocks x 256 thr (8 blocks/CU, 32 waves/CU).
// ---------------------------------------------------------------------------
__global__ __launch_bounds__(256) void psum_kernel(
    const float* __restrict__ v, const float* __restrict__ alpha,
    const float* __restrict__ kk, float* __restrict__ ws) {
  __shared__ float w_t[C_LEN][N_DIM];
  __shared__ float v_t[C_LEN][16];
  const int bid = blockIdx.x;
  const int dt = bid & 3;
  const int b  = (bid >> 2) & 7;
  const int c  = bid >> 5;
  const int tid = threadIdx.x;

  stage_w_v(b, c, dt, tid, v, alpha, kk, ws + WS_LSUM, w_t, v_t);
  __syncthreads();

  const int dl = tid >> 4;
  const int n0 = (tid & 15) * 4;
  v4f acc = {0.f, 0.f, 0.f, 0.f};
#pragma unroll
  for (int i = 0; i < C_LEN; ++i) {
    const float vv = v_t[i][dl];
    const v4f w4 = *(const v4f*)&w_t[i][n0];
    acc.x = fmaf(vv, w4.x, acc.x);
    acc.y = fmaf(vv, w4.y, acc.y);
    acc.z = fmaf(vv, w4.z, acc.z);
    acc.w = fmaf(vv, w4.w, acc.w);
  }
  *(v4f*)(ws + WS_PSUM +
          (((size_t)c * B_DIM + b) * D_DIM + dt * 16 + dl) * N_DIM + n0) = acc;
}

// ---------------------------------------------------------------------------
// P: exclusive prefix over chunk slabs: pxs[c] = sum_{j<c} psum[j].
// 8192 float4 columns, 32 blocks x 256 thr. 16 MB of L2 traffic.
// ---------------------------------------------------------------------------
__global__ __launch_bounds__(256) void prefix_kernel(float* __restrict__ ws) {
  const int q = blockIdx.x * 256 + threadIdx.x;  // float4 column id
  v4f* __restrict__ ps  = (v4f*)(ws + WS_PSUM);
  v4f* __restrict__ pxs = (v4f*)(ws + WS_PXS);

  v4f run = {0.f, 0.f, 0.f, 0.f};
#pragma unroll 8
  for (int c = 0; c < C_CHUNKS; ++c) {
    const v4f p = ps[(size_t)c * (SLAB / 4) + q];
    pxs[(size_t)c * (SLAB / 4) + q] = run;
    run.x += p.x; run.y += p.y; run.z += p.z; run.w += p.w;
  }
}

// ---------------------------------------------------------------------------
// C: acc = pxs[c] (one 16B load), then 16-step FMA + contiguous float4 store
// from LDS tiles. Grid = 2048 blocks x 256 thr.
// ---------------------------------------------------------------------------
__global__ __launch_bounds__(256) void scan_store_kernel(
    const float* __restrict__ v, const float* __restrict__ alpha,
    const float* __restrict__ kk, const float* __restrict__ ws,
    float* __restrict__ out) {
  __shared__ float w_t[C_LEN][N_DIM];
  __shared__ float v_t[C_LEN][16];
  const int bid = blockIdx.x;
  const int dt = bid & 3;
  const int b  = (bid >> 2) & 7;
  const int c  = bid >> 5;
  const int tid = threadIdx.x;

  const int dl = tid >> 4;
  const int n0 = (tid & 15) * 4;
  const int d  = dt * 16 + dl;

  // Issue the prefix load early; it's independent of staging.
  v4f acc = *(const v4f*)(ws + WS_PXS +
                          (((size_t)c * B_DIM + b) * D_DIM + d) * N_DIM + n0);

  stage_w_v(b, c, dt, tid, v, alpha, kk, ws + WS_LSUM, w_t, v_t);
  __syncthreads();

#pragma unroll
  for (int i = 0; i < C_LEN; ++i) {
    const int t = c * C_LEN + i;
    const float vv = v_t[i][dl];
    const v4f w4 = *(const v4f*)&w_t[i][n0];
    acc.x = fmaf(vv, w4.x, acc.x);
    acc.y = fmaf(vv, w4.y, acc.y);
    acc.z = fmaf(vv, w4.z, acc.z);
    acc.w = fmaf(vv, w4.w, acc.w);
    *(v4f*)(out + (((size_t)t * B_DIM + b) * D_DIM + d) * N_DIM + n0) = acc;
  }
}

// ---------------------------------------------------------------------------
extern "C" void kernel_launch(void* const* d_in, const int* in_sizes, int n_in,
                              void* d_out, int out_size, void* d_ws, size_t ws_size,
                              hipStream_t stream) {
  const float* v     = (const float*)d_in[0];
  const float* k     = (const float*)d_in[1];
  const float* alpha = (const float*)d_in[2];
  float* out = (float*)d_out;
  float* ws  = (float*)d_ws;  // needs (WS_LSUM + 32768)*4 ~= 17 MB

  lsum_kernel<<<B_DIM * C_CHUNKS, 64, 0, stream>>>(alpha, ws + WS_LSUM);
  psum_kernel<<<C_CHUNKS * B_DIM * 4, 256, 0, stream>>>(v, alpha, k, ws);
  prefix_kernel<<<SLAB / 4 / 256, 256, 0, stream>>>(ws);
  scan_store_kernel<<<C_CHUNKS * B_DIM * 4, 256, 0, stream>>>(v, alpha, k, ws, out);
}